// Round 7
// baseline (311.298 us; speedup 1.0000x reference)
//
#include <hip/hip_runtime.h>

#define L 4096
#define D 512
#define NCH 16   // context n-chunks (256 n per chunk)

typedef __bf16 bf16x8 __attribute__((ext_vector_type(8)));
typedef float  f32x4  __attribute__((ext_vector_type(4)));

__device__ __forceinline__ void load_lds16(const void* g, void* l) {
    __builtin_amdgcn_global_load_lds(
        (const __attribute__((address_space(1))) void*)g,
        (__attribute__((address_space(3))) void*)l, 16, 0, 0);
}

// ---------------------------------------------------------------------------
// weights-only f32 -> bf16 (Wqkv then Wout into contiguous dst). grid 512.
// ---------------------------------------------------------------------------
#define NW18 (1536 * 512 / 8)
#define NW28 (512 * 512 / 8)
__global__ __launch_bounds__(256) void convert_w(const float* __restrict__ Wq,
                                                 const float* __restrict__ Wo,
                                                 __bf16* __restrict__ dst) {
    int i = blockIdx.x * 256 + threadIdx.x;
    if (i >= NW18 + NW28) return;
    const float* s = (i < NW18) ? Wq + (size_t)i * 8 : Wo + (size_t)(i - NW18) * 8;
    float4 a = ((const float4*)s)[0], b = ((const float4*)s)[1];
    bf16x8 o = {(__bf16)a.x, (__bf16)a.y, (__bf16)a.z, (__bf16)a.w,
                (__bf16)b.x, (__bf16)b.y, (__bf16)b.z, (__bf16)b.w};
    *(bf16x8*)(dst + (size_t)i * 8) = o;
}

// ---------------------------------------------------------------------------
// qkv GEMM with fused x conversion:
// qkv[b][m][n] = sum_k Wq[m][k] * x[b][n][k]; A bf16 via global_load_lds,
// B f32 via reg-cvt-ds_write. 128x128 tile, BK=32, XOR-swizzled LDS.
// ---------------------------------------------------------------------------
__global__ __launch_bounds__(256) void qkv_gemm_xf32(
    const __bf16* __restrict__ Wq,   // [1536][512] bf16
    const float* __restrict__ x,     // [8][4096][512] f32
    __bf16* __restrict__ qkv) {      // [8][1536][4096] bf16
    __shared__ __align__(16) __bf16 sA[128 * 32];
    __shared__ __align__(16) __bf16 sB[128 * 32];
    const int b  = blockIdx.z;
    const int m0 = blockIdx.y * 128;
    const int n0 = blockIdx.x * 128;
    const int t    = threadIdx.x;
    const int wave = t >> 6, lane = t & 63;
    const int wm = (wave & 1) * 64, wn = (wave >> 1) * 64;
    const float* xb = x + (size_t)b * L * D;
    __bf16* Cb = qkv + (size_t)b * 1536 * L;

    f32x4 acc[4][4];
#pragma unroll
    for (int i = 0; i < 4; i++)
#pragma unroll
        for (int j = 0; j < 4; j++) acc[i][j] = (f32x4)(0.0f);

    const int fr = lane & 15;
    const int cq = lane >> 4;
    const int ko = (cq ^ ((fr >> 1) & 3)) * 8;

    for (int k0 = 0; k0 < D; k0 += 32) {
        __syncthreads();
#pragma unroll
        for (int c = 0; c < 2; c++) {
            const int idx = c * 256 + t;
            const int row = idx >> 2, cc = idx & 3;
            const int scc = cc ^ ((row >> 1) & 3);
            // A: DMA bf16 16B
            load_lds16(Wq + (size_t)(m0 + row) * D + k0 + scc * 8, &sA[idx * 8]);
            // B: f32 load + cvt + lane-contiguous 16B LDS write (conflict-free)
            const float4* src = (const float4*)(xb + (size_t)(n0 + row) * D + k0 + scc * 8);
            float4 lo = src[0], hi = src[1];
            bf16x8 o = {(__bf16)lo.x, (__bf16)lo.y, (__bf16)lo.z, (__bf16)lo.w,
                        (__bf16)hi.x, (__bf16)hi.y, (__bf16)hi.z, (__bf16)hi.w};
            *(bf16x8*)&sB[idx * 8] = o;
        }
        __syncthreads();
        bf16x8 af[4], bfr[4];
#pragma unroll
        for (int i = 0; i < 4; i++) {
            af[i]  = *(const bf16x8*)&sA[(wm + i * 16 + fr) * 32 + ko];
            bfr[i] = *(const bf16x8*)&sB[(wn + i * 16 + fr) * 32 + ko];
        }
#pragma unroll
        for (int i = 0; i < 4; i++)
#pragma unroll
            for (int j = 0; j < 4; j++)
                acc[i][j] = __builtin_amdgcn_mfma_f32_16x16x32_bf16(af[i], bfr[j], acc[i][j], 0, 0, 0);
    }

    const int col = lane & 15, rbase = (lane >> 4) * 4;
#pragma unroll
    for (int j = 0; j < 4; j++) {
        const int n = n0 + wn + j * 16 + col;
#pragma unroll
        for (int i = 0; i < 4; i++) {
#pragma unroll
            for (int r = 0; r < 4; r++) {
                const int m = m0 + wm + i * 16 + rbase + r;
                Cb[(size_t)m * L + n] = (__bf16)acc[i][j][r];
            }
        }
    }
}

// ---------------------------------------------------------------------------
// Generic TN bf16 MFMA GEMM (BK=32, XOR swizzle). Used for the out-proj.
// ---------------------------------------------------------------------------
template <int M, int N, int K, typename CT>
__global__ __launch_bounds__(256) void gemm_bf16_mfma(
    const __bf16* __restrict__ A, size_t aStride,
    const __bf16* __restrict__ B, size_t bStride,
    CT* __restrict__ C, size_t cStride,
    const float* __restrict__ bias) {
    __shared__ __align__(16) __bf16 sA[128 * 32];
    __shared__ __align__(16) __bf16 sB[128 * 32];
    const int b  = blockIdx.z;
    const int m0 = blockIdx.y * 128;
    const int n0 = blockIdx.x * 128;
    const int t    = threadIdx.x;
    const int wave = t >> 6, lane = t & 63;
    const int wm = (wave & 1) * 64, wn = (wave >> 1) * 64;
    const __bf16* Ab = A + (size_t)b * aStride;
    const __bf16* Bb = B + (size_t)b * bStride;
    CT* Cb = C + (size_t)b * cStride;

    f32x4 acc[4][4];
#pragma unroll
    for (int i = 0; i < 4; i++)
#pragma unroll
        for (int j = 0; j < 4; j++) acc[i][j] = (f32x4)(0.0f);

    const int fr = lane & 15;
    const int cq = lane >> 4;
    const int ko = (cq ^ ((fr >> 1) & 3)) * 8;

    for (int k0 = 0; k0 < K; k0 += 32) {
        __syncthreads();
#pragma unroll
        for (int c = 0; c < 2; c++) {
            const int idx = c * 256 + t;
            const int row = idx >> 2, cc = idx & 3;
            const int scc = cc ^ ((row >> 1) & 3);
            load_lds16(Ab + (size_t)(m0 + row) * K + k0 + scc * 8, &sA[idx * 8]);
            load_lds16(Bb + (size_t)(n0 + row) * K + k0 + scc * 8, &sB[idx * 8]);
        }
        __syncthreads();
        bf16x8 af[4], bfr[4];
#pragma unroll
        for (int i = 0; i < 4; i++) {
            af[i]  = *(const bf16x8*)&sA[(wm + i * 16 + fr) * 32 + ko];
            bfr[i] = *(const bf16x8*)&sB[(wn + i * 16 + fr) * 32 + ko];
        }
#pragma unroll
        for (int i = 0; i < 4; i++)
#pragma unroll
            for (int j = 0; j < 4; j++)
                acc[i][j] = __builtin_amdgcn_mfma_f32_16x16x32_bf16(af[i], bfr[j], acc[i][j], 0, 0, 0);
    }

    const int col = lane & 15, rbase = (lane >> 4) * 4;
#pragma unroll
    for (int j = 0; j < 4; j++) {
        const int n = n0 + wn + j * 16 + col;
        const float bv = bias ? bias[n] : 0.0f;
#pragma unroll
        for (int i = 0; i < 4; i++) {
#pragma unroll
            for (int r = 0; r < 4; r++) {
                const int m = m0 + wm + i * 16 + rbase + r;
                Cb[(size_t)m * N + n] = (CT)(acc[i][j][r] + bv);
            }
        }
    }
}

// ---------------------------------------------------------------------------
// k-row stats over bf16 k rows: per row compute (max, 1/sumexp). grid 4096.
// ---------------------------------------------------------------------------
__global__ __launch_bounds__(256) void kstats(const __bf16* __restrict__ qkv,
                                              float2* __restrict__ stats) {
    const int r = blockIdx.x;
    const int b = r >> 9, hc = r & 511;
    const __bf16* row = qkv + (size_t)b * 1536 * L + (size_t)(512 + hc) * L;
    __shared__ float sred[4];
    const int t = threadIdx.x;
    const bf16x8* p = (const bf16x8*)row;
    bf16x8 c0 = p[t * 2], c1 = p[t * 2 + 1];
    float v[16];
    float m = -1e30f;
#pragma unroll
    for (int j = 0; j < 8; j++) {
        v[j] = (float)c0[j];
        v[8 + j] = (float)c1[j];
    }
#pragma unroll
    for (int j = 0; j < 16; j++) m = fmaxf(m, v[j]);
#pragma unroll
    for (int off = 32; off > 0; off >>= 1) m = fmaxf(m, __shfl_down(m, off, 64));
    if ((t & 63) == 0) sred[t >> 6] = m;
    __syncthreads();
    const float m4 = fmaxf(fmaxf(sred[0], sred[1]), fmaxf(sred[2], sred[3]));
    float s = 0.f;
#pragma unroll
    for (int j = 0; j < 16; j++) s += __expf(v[j] - m4);
#pragma unroll
    for (int off = 32; off > 0; off >>= 1) s += __shfl_down(s, off, 64);
    __syncthreads();
    if ((t & 63) == 0) sred[t >> 6] = s;
    __syncthreads();
    if (t == 0) {
        const float stot = sred[0] + sred[1] + sred[2] + sred[3];
        stats[r] = make_float2(m4, 1.0f / stot);
    }
}

// ---------------------------------------------------------------------------
// MFMA context partials: ctxp[chunk][bh][d][e] (f32, d-major) =
//   sum_{n in chunk} exp(k[d,n]-m_d) * v[e,n]   (un-normalized; 1/s at reduce)
// ---------------------------------------------------------------------------
#define SKS 264   // LDS bf16 row stride (256 data + 8 pad)
__global__ __launch_bounds__(256) void context_mfma(const __bf16* __restrict__ qkv,
                                                    const float2* __restrict__ stats,
                                                    float* __restrict__ ctxp) {
    __shared__ __align__(16) __bf16 smem[2 * 64 * SKS];  // reused as f32 red[4][4096]
    __shared__ float smax[64];
    __bf16* sk = smem;
    __bf16* sv = smem + 64 * SKS;
    const int chunk = blockIdx.x;
    const int bh = blockIdx.y;
    const int b = bh >> 3, h = bh & 7;
    const __bf16* kbase = qkv + (size_t)b * 1536 * L + (size_t)(512 + h * 64) * L;
    const __bf16* vbase = qkv + (size_t)b * 1536 * L + (size_t)(1024 + h * 64) * L;
    const int t = threadIdx.x;
    if (t < 64) smax[t] = stats[bh * 64 + t].x;
    __syncthreads();

    {
        const int d = t >> 2, noff = (t & 3) * 64;
        const int n0 = chunk * 256;
        const __bf16* kp = kbase + (size_t)d * L + n0 + noff;
        const __bf16* vp = vbase + (size_t)d * L + n0 + noff;
        const float md = smax[d];
#pragma unroll
        for (int c = 0; c < 8; c++) {
            bf16x8 kk = *(const bf16x8*)(kp + c * 8);
            bf16x8 vv = *(const bf16x8*)(vp + c * 8);
            bf16x8 ek;
#pragma unroll
            for (int j = 0; j < 8; j++) ek[j] = (__bf16)__expf((float)kk[j] - md);
            *(bf16x8*)&sk[d * SKS + noff + c * 8] = ek;
            *(bf16x8*)&sv[d * SKS + noff + c * 8] = vv;
        }
    }
    __syncthreads();

    const int wave = t >> 6, lane = t & 63;
    const int fr = lane & 15, kq = (lane >> 4) * 8;
    f32x4 acc[4][4];
#pragma unroll
    for (int i = 0; i < 4; i++)
#pragma unroll
        for (int j = 0; j < 4; j++) acc[i][j] = (f32x4)(0.0f);
#pragma unroll
    for (int kh = 0; kh < 2; kh++) {
        const int koff = wave * 64 + kh * 32 + kq;
        bf16x8 af[4], bfr[4];
#pragma unroll
        for (int i = 0; i < 4; i++) {
            af[i]  = *(const bf16x8*)&sk[(i * 16 + fr) * SKS + koff];
            bfr[i] = *(const bf16x8*)&sv[(i * 16 + fr) * SKS + koff];
        }
#pragma unroll
        for (int i = 0; i < 4; i++)
#pragma unroll
            for (int j = 0; j < 4; j++)
                acc[i][j] = __builtin_amdgcn_mfma_f32_16x16x32_bf16(af[i], bfr[j], acc[i][j], 0, 0, 0);
    }
    __syncthreads();

    float* red = (float*)smem;
    const int col = lane & 15, rbase = (lane >> 4) * 4;
#pragma unroll
    for (int i = 0; i < 4; i++)
#pragma unroll
        for (int j = 0; j < 4; j++)
#pragma unroll
            for (int r = 0; r < 4; r++) {
                const int dd = i * 16 + rbase + r;
                const int ee = j * 16 + col;
                red[wave * 4096 + dd * 64 + ee] = acc[i][j][r];
            }
    __syncthreads();
    float* cp = ctxp + ((size_t)chunk * 64 + bh) * 4096;
#pragma unroll
    for (int gg = 0; gg < 4; gg++) {
        const int idx = t * 16 + gg * 4;
        f32x4 s = *(const f32x4*)&red[idx];
        s += *(const f32x4*)&red[4096 + idx];
        s += *(const f32x4*)&red[8192 + idx];
        s += *(const f32x4*)&red[12288 + idx];
        *(f32x4*)&cp[idx] = s;
    }
}

// ---------------------------------------------------------------------------
// reduce ctx partials over chunks, apply 1/s_d, transpose [d][e]->[e][d],
// emit bf16 ctxT[bh][e][d]. grid 256.
// ---------------------------------------------------------------------------
__global__ __launch_bounds__(256) void ctx_reduce(const float* __restrict__ ctxp,
                                                  const float2* __restrict__ stats,
                                                  __bf16* __restrict__ ctxT) {
    const int bh = blockIdx.x >> 2, quarter = blockIdx.x & 3;
    const int t = threadIdx.x;
    const int flat = quarter * 1024 + t * 4;
    const int d = flat >> 6, e0 = flat & 63;
    f32x4 s = (f32x4)(0.0f);
    for (int ch = 0; ch < NCH; ch++)
        s += *(const f32x4*)&ctxp[((size_t)ch * 64 + bh) * 4096 + flat];
    const float inv = stats[bh * 64 + d].y;
    __bf16* o = ctxT + (size_t)bh * 4096;
#pragma unroll
    for (int j = 0; j < 4; j++) o[(e0 + j) * 64 + d] = (__bf16)(s[j] * inv);
}

// ---------------------------------------------------------------------------
// pv_fused: per (bh, 256-col tile): q-softmax (unnormalized exp in LDS bf16)
// + MFMA 256x64 K=64 against ctxT, normalize in epilogue, write bf16 outT.
// ---------------------------------------------------------------------------
#define SPS 66   // LDS row stride (bf16)
__global__ __launch_bounds__(256) void pv_fused(__bf16* __restrict__ qkv,
                                                const __bf16* __restrict__ ctxT) {
    __shared__ __align__(16) __bf16 sp[256 * SPS];
    __shared__ __align__(16) __bf16 sctx[64 * SPS];
    __shared__ float sinv[256];
    const int tileN = blockIdx.x;
    const int bh = blockIdx.y;
    const int b = bh >> 3, h = bh & 7;
    const int t = threadIdx.x;
    const int n0 = tileN * 256;
    const __bf16* qbase = qkv + (size_t)b * 1536 * L + (size_t)(h * 64) * L;

    {
        const int e = t >> 2, c = t & 3;
        const bf16x8* src = (const bf16x8*)(ctxT + ((size_t)bh * 64 + e) * 64 + c * 16);
        *(bf16x8*)&sctx[e * SPS + c * 16] = src[0];
        *(bf16x8*)&sctx[e * SPS + c * 16 + 8] = src[1];
    }

    float m = -1e30f;
    float qv[64];
#pragma unroll
    for (int d = 0; d < 64; d++) {
        qv[d] = (float)qbase[(size_t)d * L + n0 + t];
        m = fmaxf(m, qv[d]);
    }
    float s = 0.f;
#pragma unroll
    for (int d0 = 0; d0 < 64; d0 += 8) {
        bf16x8 ek;
#pragma unroll
        for (int j = 0; j < 8; j++) {
            float e = __expf(qv[d0 + j] - m);
            s += e;
            ek[j] = (__bf16)e;
        }
        *(bf16x8*)&sp[t * SPS + d0] = ek;
    }
    sinv[t] = 1.0f / s;
    __syncthreads();

    const int wave = t >> 6, lane = t & 63;
    const int wm = wave * 64;
    const int fr = lane & 15, kq = (lane >> 4) * 8;
    f32x4 acc[4][4];
#pragma unroll
    for (int i = 0; i < 4; i++)
#pragma unroll
        for (int j = 0; j < 4; j++) acc[i][j] = (f32x4)(0.0f);
#pragma unroll
    for (int kh = 0; kh < 2; kh++) {
        bf16x8 af[4], bfr[4];
#pragma unroll
        for (int i = 0; i < 4; i++)
            af[i] = *(const bf16x8*)&sp[(wm + i * 16 + fr) * SPS + kh * 32 + kq];
#pragma unroll
        for (int j = 0; j < 4; j++)
            bfr[j] = *(const bf16x8*)&sctx[(j * 16 + fr) * SPS + kh * 32 + kq];
#pragma unroll
        for (int i = 0; i < 4; i++)
#pragma unroll
            for (int j = 0; j < 4; j++)
                acc[i][j] = __builtin_amdgcn_mfma_f32_16x16x32_bf16(af[i], bfr[j], acc[i][j], 0, 0, 0);
    }

    __bf16* ob = qkv + (size_t)b * 1536 * L + (size_t)512 * L;
    const int col = lane & 15, rbase = (lane >> 4) * 4;
#pragma unroll
    for (int i = 0; i < 4; i++) {
#pragma unroll
        for (int r = 0; r < 4; r++) {
            const int nl = wm + i * 16 + rbase + r;
            const float inv = sinv[nl];
            const size_t rowoff = (size_t)(n0 + nl) * 512 + h * 64;
#pragma unroll
            for (int j = 0; j < 4; j++)
                ob[rowoff + j * 16 + col] = (__bf16)(acc[i][j][r] * inv);
        }
    }
}

// ---------------------------------------------------------------------------
extern "C" void kernel_launch(void* const* d_in, const int* in_sizes, int n_in,
                              void* d_out, int out_size, void* d_ws, size_t ws_size,
                              hipStream_t stream) {
    const float* x    = (const float*)d_in[0];
    const float* Wqkv = (const float*)d_in[1];
    const float* Wout = (const float*)d_in[2];
    const float* bout = (const float*)d_in[3];
    float* y = (float*)d_out;

    __bf16* qkv   = (__bf16*)d_ws;                               // 8*1536*4096 bf16
    float*  ctxp  = (float*)(qkv + (size_t)8 * 1536 * L);        // NCH*64*4096 f32
    __bf16* Wqb   = (__bf16*)(ctxp + (size_t)NCH * 64 * 4096);   // 1536*512 bf16
    __bf16* Wob   = Wqb + (size_t)1536 * 512;                    // 512*512 bf16
    float2* stats = (float2*)(Wob + (size_t)512 * 512);          // 4096 float2
    __bf16* ctxT  = (__bf16*)(stats + 4096);                     // 64*4096 bf16

    convert_w<<<dim3((NW18 + NW28 + 255) / 256), 256, 0, stream>>>(Wqkv, Wout, Wqb);

    // qkv[b][o][l] = sum_d Wqkv[o][d] * x[b][l][d]  — x converted in-kernel
    qkv_gemm_xf32<<<dim3(4096 / 128, 1536 / 128, 8), 256, 0, stream>>>(Wqb, x, qkv);

    kstats<<<dim3(4096), 256, 0, stream>>>(qkv, stats);
    context_mfma<<<dim3(NCH, 64), 256, 0, stream>>>(qkv, stats, ctxp);
    ctx_reduce<<<dim3(256), 256, 0, stream>>>(ctxp, stats, ctxT);
    pv_fused<<<dim3(L / 256, 64), 256, 0, stream>>>(qkv, ctxT);

    // y[b][l][d] = sum_c outT[b][l][c] * Wout[d][c] + bout[d]
    const __bf16* outT = qkv + (size_t)512 * L;
    gemm_bf16_mfma<4096, 512, 512, float><<<dim3(512 / 128, 4096 / 128, 8), 256, 0, stream>>>(
        outT, (size_t)1536 * L, Wob, 0, y, (size_t)4096 * 512, bout);
}